// Round 6
// baseline (275.187 us; speedup 1.0000x reference)
//
#include <hip/hip_runtime.h>

#define SEQ 4096
#define NBATCH 256

__device__ __forceinline__ float sqf(float v) { return v * v; }
__device__ __forceinline__ float fexp2(float v) { return __builtin_amdgcn_exp2f(v); }
__device__ __forceinline__ float frcp(float v)  { return __builtin_amdgcn_rcpf(v); }

#define L2E 1.4426950408889634f

// order-preserving float<->uint key for atomicMax on floats
__device__ __forceinline__ unsigned fkey(float f) {
    const int b = __float_as_int(f);
    return (unsigned)(b ^ ((b >> 31) | 0x80000000));
}
__device__ __forceinline__ float fival(unsigned k) {
    const int b = (k & 0x80000000u) ? (int)(k ^ 0x80000000u) : (int)(~k);
    return __int_as_float(b);
}

// ---------------------------------------------------------------------------
// Kernel 0: fold the 24-wide input matvec into 12 inputs + bias, pre-scaled
// by the row's activation pre-scale (-log2e; -2log2e for g rows).
// Layout Wp[(d*40 + r)*16 + k] -- 16-padded rows so the lstm producer can
// s_load row quads. Also zero-initializes the MMu atomic-max buffer.
// ---------------------------------------------------------------------------
__global__ void wprep_kernel(
    const float* __restrict__ Wih_f, const float* __restrict__ bih_f,
    const float* __restrict__ bhh_f,
    const float* __restrict__ Wih_r, const float* __restrict__ bih_r,
    const float* __restrict__ bhh_r,
    float* __restrict__ Wp, unsigned* __restrict__ MMu)
{
    const int t = threadIdx.x;
    for (int i = t; i < NBATCH * 5; i += 256) MMu[i] = 0u;  // key 0 < any real
    if (t >= 80) return;
    const int d = t / 40, r = t % 40;
    const float* __restrict__ W  = (d ? Wih_r : Wih_f) + r * 24;
    const float* __restrict__ bi = d ? bih_r : bih_f;
    const float* __restrict__ bh = d ? bhh_r : bhh_f;
    const float sc = (r >= 20 && r < 30) ? (-2.f * L2E) : (-L2E);
    float o[13];
    o[0]  = W[0] + W[1] + W[2] + W[3];                // v4s
    o[1]  = W[4] + W[5] + W[6] + W[7];                // v5s
    o[2]  = W[4];                                     // v5p
    o[3]  = W[8] + W[9] + W[10] + W[11];              // v6s
    o[4]  = W[8] + W[9];                              // v6p
    o[5]  = W[12] + W[13] + W[14] + W[15];            // v7s
    o[6]  = W[12] + W[13] + W[14];                    // v7p
    o[7]  = W[16] + W[17] + W[18] + W[19];            // v8s+v8p
    o[8]  = W[20]; o[9] = W[21]; o[10] = W[22]; o[11] = W[23];   // x0..x3
    o[12] = bi[r] + bh[r];
    float* __restrict__ out = Wp + (d * 40 + r) * 16;
#pragma unroll
    for (int k = 0; k < 13; ++k) out[k] = o[k] * sc;
    out[13] = 0.f; out[14] = 0.f; out[15] = 0.f;
}

// ---------------------------------------------------------------------------
// Kernel 1a: per-batch conv max -> atomicMax on uint keys.
// ---------------------------------------------------------------------------
__global__ __launch_bounds__(256) void max_kernel(
    const float* __restrict__ x,
    const float* __restrict__ w4p, const float* __restrict__ w5p,
    const float* __restrict__ w6p, const float* __restrict__ w7p,
    const float* __restrict__ w8p,
    unsigned* __restrict__ MMu)
{
    const int b    = blockIdx.x >> 2;
    const int quar = blockIdx.x & 3;
    const int tid  = threadIdx.x;
    const float* __restrict__ xr = x + (size_t)b * (4 * SEQ);

    float W4[4], W5[5], W6[6], W7[7], W8[8];
#pragma unroll
    for (int k = 0; k < 4; ++k) W4[k] = w4p[k];
#pragma unroll
    for (int k = 0; k < 5; ++k) W5[k] = w5p[k];
#pragma unroll
    for (int k = 0; k < 6; ++k) W6[k] = w6p[k];
#pragma unroll
    for (int k = 0; k < 7; ++k) W7[k] = w7p[k];
#pragma unroll
    for (int k = 0; k < 8; ++k) W8[k] = w8p[k];

    float m4 = -3.4e38f, m5 = -3.4e38f, m6 = -3.4e38f, m7 = -3.4e38f, m8 = -3.4e38f;
    for (int i = quar * (SEQ / 4) + tid; i < (quar + 1) * (SEQ / 4); i += 256) {
        const float4 t0 = *reinterpret_cast<const float4*>(xr + 4 * i);
        const float xa0 = t0.x, xa1 = t0.y, xa2 = t0.z, xa3 = t0.w;
        const float c4 = xa0 * W4[0] + xa1 * W4[1] + xa2 * W4[2] + xa3 * W4[3];
        m4 = fmaxf(m4, c4);
        if (i < SEQ - 1) {
            const float4 t1 = *reinterpret_cast<const float4*>(xr + 4 * i + 4);
            const float xa4 = t1.x, xa5 = t1.y, xa6 = t1.z, xa7 = t1.w;
            const float c5 = xa0*W5[0]+xa1*W5[1]+xa2*W5[2]+xa3*W5[3]+xa4*W5[4];
            const float c6 = xa0*W6[0]+xa1*W6[1]+xa2*W6[2]+xa3*W6[3]+xa4*W6[4]+xa5*W6[5];
            const float c7 = xa0*W7[0]+xa1*W7[1]+xa2*W7[2]+xa3*W7[3]+xa4*W7[4]+xa5*W7[5]+xa6*W7[6];
            const float c8 = xa0*W8[0]+xa1*W8[1]+xa2*W8[2]+xa3*W8[3]+xa4*W8[4]+xa5*W8[5]+xa6*W8[6]+xa7*W8[7];
            m5 = fmaxf(m5, c5); m6 = fmaxf(m6, c6);
            m7 = fmaxf(m7, c7); m8 = fmaxf(m8, c8);
        }
    }
#pragma unroll
    for (int off = 32; off; off >>= 1) {
        m4 = fmaxf(m4, __shfl_down(m4, off));
        m5 = fmaxf(m5, __shfl_down(m5, off));
        m6 = fmaxf(m6, __shfl_down(m6, off));
        m7 = fmaxf(m7, __shfl_down(m7, off));
        m8 = fmaxf(m8, __shfl_down(m8, off));
    }
    __shared__ float wr[4][5];
    if ((tid & 63) == 0) {
        const int w = tid >> 6;
        wr[w][0] = m4; wr[w][1] = m5; wr[w][2] = m6; wr[w][3] = m7; wr[w][4] = m8;
    }
    __syncthreads();
    if (tid < 5) {
        const float m = fmaxf(fmaxf(wr[0][tid], wr[1][tid]),
                              fmaxf(wr[2][tid], wr[3][tid]));
        atomicMax(&MMu[b * 5 + tid], fkey(m));
    }
}

// ---------------------------------------------------------------------------
// Kernel 2 (r6): fused LSTM, producer with SGPR weights + LDS-pinned
// h-weights.
// r5 post-mortem: 204 VALU instrs/step vs ~110 fundamental -> weight
// residency bloat (VGPR 104 < 92 weights + temps). This round makes the
// pressure structurally small:
//  (a) input matvec runs in the PRODUCER phase with SGPR weight operands
//      (v_fmac v,s,v; weights s_loaded from wprep's padded rows) -- 520
//      weights occupy ZERO VGPRs, no operand movs, 30 fma/step vs 48.
//  (b) the 40 h-weights are read from LDS (wlds) once; in-loop hb writes
//      alias LDS so LLVM cannot rematerialize them -> truly resident.
//  (c) gbuf laid out [i][c][44] so all unrolled step reads share one base
//      register + immediate offsets (zero per-step address math).
//  (d) conv stays fused (r5 win: FETCH 8MB, no lin buffer).
// All accumulation orders bit-identical to r5 -> absmax 0.
// Grid = 16 seg x 2 dir x 64 bgroups = 2048 x 64, 2 waves/SIMD;
// own=256, warm=128; seg0 exact reset preserved.
// ---------------------------------------------------------------------------
__global__ __launch_bounds__(64) __attribute__((amdgpu_waves_per_eu(2, 2)))
void lstm_kernel(
    const float* __restrict__ x,
    const float* __restrict__ w4p, const float* __restrict__ w5p,
    const float* __restrict__ w6p, const float* __restrict__ w7p,
    const float* __restrict__ w8p,
    const unsigned* __restrict__ MMu,
    const float* __restrict__ Wp,
    const float* __restrict__ Whh_f, const float* __restrict__ Whh_r,
    float* __restrict__ P)
{
    const int bg   = blockIdx.x & 63;
    const int d    = (blockIdx.x >> 6) & 1;
    const int q    = blockIdx.x >> 7;          // 0..15 = segment
    const int b0   = bg * 4;
    const int lane = threadIdx.x;

    const int s0 = q * 256 - 128;              // negative for q=0 (clamped)
    const int nChunks = 24, warmChunks = 8;    // 16-step chunks, 384 steps

    __shared__ __align__(16) float gbuf[16 * 4 * 44];  // [i][c][44]
    __shared__ __align__(16) float hb[64];             // [chain][16] h state
    __shared__ __align__(16) float wlds[400];          // [u][k][gate] quads

    const int c  = lane >> 4;
    const int jr = lane & 15;
    const int jc = (jr < 10) ? jr : 0;

    hb[lane] = 0.f;

    // ---- stage folded h-weights into LDS (one-time) ----
    {
        const float* __restrict__ Whh = d ? Whh_r : Whh_f;
        for (int idx = lane; idx < 400; idx += 64) {
            const int g   = idx / 100;
            const int rem = idx - g * 100;
            const int u = rem / 10, k = rem - u * 10;
            const float sc = (g == 2) ? (-2.f * L2E) : (-L2E);
            wlds[(u * 10 + k) * 4 + g] = Whh[(g * 10 + u) * 10 + k] * sc;
        }
    }
    asm volatile("s_waitcnt lgkmcnt(0)" ::: "memory");

    // per-lane h weights (LDS-sourced: hb writes alias -> not rematable)
    float hI[10], hF[10], hG[10], hO[10];
#pragma unroll
    for (int k = 0; k < 10; ++k) {
        const float4 w = *reinterpret_cast<const float4*>(&wlds[(jc * 10 + k) * 4]);
        hI[k] = w.x; hF[k] = w.y; hG[k] = w.z; hO[k] = w.w;
    }

    // ---- producer setup: lane stages row (step lane>>2, chain lane&3) ----
    const int lc = lane & 3;
    const int lr = lane >> 2;                  // 0..15
    const float* __restrict__ xr = x + (size_t)(b0 + lc) * (4 * SEQ);
    const float* __restrict__ Wd = Wp + d * 640;   // uniform -> s_loads

    float W4[4], W5[5], W6[6], W7[7], W8[8];
#pragma unroll
    for (int k = 0; k < 4; ++k) W4[k] = w4p[k];
#pragma unroll
    for (int k = 0; k < 5; ++k) W5[k] = w5p[k];
#pragma unroll
    for (int k = 0; k < 6; ++k) W6[k] = w6p[k];
#pragma unroll
    for (int k = 0; k < 7; ++k) W7[k] = w7p[k];
#pragma unroll
    for (int k = 0; k < 8; ++k) W8[k] = w8p[k];

    const float M4 = fival(MMu[(b0 + lc) * 5 + 0]);
    const float M5 = fival(MMu[(b0 + lc) * 5 + 1]);
    const float M6 = fival(MMu[(b0 + lc) * 5 + 2]);
    const float M7 = fival(MMu[(b0 + lc) * 5 + 3]);
    const float M8 = fival(MMu[(b0 + lc) * 5 + 4]);

    auto posof = [&](int cn) {
        int sp = s0 + cn * 16 + lr;
        if (sp < 0) sp = 0;                    // q=0 warm region: clamped garbage,
                                               // discarded by the state reset
        return d ? (SEQ - 1 - sp) : sp;
    };
    auto loadx = [&](int pos, float4& A, float4& B, float4& C) {
        B = *reinterpret_cast<const float4*>(xr + 4 * pos);
        A = (pos > 0) ? *reinterpret_cast<const float4*>(xr + 4 * pos - 4)
                      : make_float4(0.f, 0.f, 0.f, 0.f);
        C = (pos < SEQ - 1) ? *reinterpret_cast<const float4*>(xr + 4 * pos + 4)
                            : make_float4(0.f, 0.f, 0.f, 0.f);
    };

    int posCur = posof(0);
    float4 xA, xB, xC;
    loadx(posCur, xA, xB, xC);

    // fixed LDS base pointers (per-step access = base + immediate offset)
    float* __restrict__ gw        = &gbuf[(lr * 4 + lc) * 44];   // producer write
    const float* __restrict__ grd = &gbuf[c * 44 + jc * 4];      // gate read
    const float* __restrict__ sxr = &gbuf[c * 44 + 40];          // xsum read

    float cs = 0.f, accS = 0.f;

    // one recurrence step; h round-trips through hb (same-wave DS in-order)
    auto step = [&](int i) {
        const float4 g4 = *reinterpret_cast<const float4*>(grd + i * 176);
        const float  sx = sxr[i * 176];
        const float4 h03 = *reinterpret_cast<const float4*>(&hb[c * 16 + 0]);
        const float4 h47 = *reinterpret_cast<const float4*>(&hb[c * 16 + 4]);
        const float2 h89 = *reinterpret_cast<const float2*>(&hb[c * 16 + 8]);
        const float hj[10] = {h03.x, h03.y, h03.z, h03.w,
                              h47.x, h47.y, h47.z, h47.w, h89.x, h89.y};
        // h-matvec (same even/odd accumulation order as r5)
        float ai0 = g4.x, ai1 = 0.f, af0 = g4.y, af1 = 0.f;
        float ag0 = g4.z, ag1 = 0.f, ao0 = g4.w, ao1 = 0.f;
#pragma unroll
        for (int k = 0; k < 10; k += 2) {
            ai0 = fmaf(hj[k], hI[k], ai0); ai1 = fmaf(hj[k + 1], hI[k + 1], ai1);
            af0 = fmaf(hj[k], hF[k], af0); af1 = fmaf(hj[k + 1], hF[k + 1], af1);
            ag0 = fmaf(hj[k], hG[k], ag0); ag1 = fmaf(hj[k + 1], hG[k + 1], ag1);
            ao0 = fmaf(hj[k], hO[k], ao0); ao1 = fmaf(hj[k + 1], hO[k + 1], ao1);
        }
        const float eI = ai0 + ai1, eF = af0 + af1;
        const float eG = ag0 + ag1, eO = ao0 + ao1;
        // eI=-l2e*i  eF=-l2e*f  eG=-2l2e*g  eO=-l2e*o
        const float Ai = fexp2(eI);                    // e^-i
        const float Fv = fexp2(eF);                    // e^-f
        const float Bg = fexp2(fminf(eG, 80.f));       // e^-2g (clamped: no inf*0)
        const float Ov = fexp2(eO);                    // e^-o
        const float sf = frcp(1.f + Fv);
        // -2l2e * sigmoid(i)*tanh(g) = (2l2e*Bg - 2l2e) / ((1+Ai)(1+Bg))
        const float it = fmaf(Bg, 2.f * L2E, -2.f * L2E) *
                         frcp((1.f + Ai) * (1.f + Bg));
        cs = fmaf(sf, cs, it);                         // cs = -2l2e * c
        const float Dv = fexp2(fminf(cs, 80.f));       // e^-2c (clamped)
        // sigmoid(o)*tanh(c) = (1-Dv) / ((1+Ov)(1+Dv))
        const float hv = (1.f - Dv) * frcp((1.f + Ov) * (1.f + Dv));
        hb[c * 16 + jr] = hv;                          // jr>=10 -> harmless pad
        accS = fmaf(sx, hv, accS);
    };

    for (int cn = 0; cn < nChunks; ++cn) {
        // ---- producer: conv (r5 math, exact order) -> row values vv ----
        float vv[12], xsum;
        {
            const bool okp = posCur > 0, oks = posCur < SEQ - 1;
            float xw[12];
            xw[0] = xA.x; xw[1] = xA.y; xw[2]  = xA.z; xw[3]  = xA.w;
            xw[4] = xB.x; xw[5] = xB.y; xw[6]  = xB.z; xw[7]  = xB.w;
            xw[8] = xC.x; xw[9] = xC.y; xw[10] = xC.z; xw[11] = xC.w;

            float c4s = 0.f, c5s = 0.f, c6s = 0.f, c7s = 0.f, c8s = 0.f;
            float c5p = 0.f, c6p = 0.f, c7p = 0.f, c8p = 0.f;
#pragma unroll
            for (int t = 0; t < 4; ++t) c4s += xw[4 + t] * W4[t];
#pragma unroll
            for (int t = 0; t < 5; ++t) { c5s += xw[4 + t] * W5[t]; c5p += xw[t] * W5[t]; }
#pragma unroll
            for (int t = 0; t < 6; ++t) { c6s += xw[4 + t] * W6[t]; c6p += xw[t] * W6[t]; }
#pragma unroll
            for (int t = 0; t < 7; ++t) { c7s += xw[4 + t] * W7[t]; c7p += xw[t] * W7[t]; }
#pragma unroll
            for (int t = 0; t < 8; ++t) { c8s += xw[4 + t] * W8[t]; c8p += xw[t] * W8[t]; }

            vv[0]  = sqf(c4s + M4);
            vv[1]  = oks ? sqf(c5s + M5) : 0.f;
            vv[2]  = okp ? sqf(c5p + M5) : 0.f;
            vv[3]  = oks ? sqf(c6s + M6) : 0.f;
            vv[4]  = okp ? sqf(c6p + M6) : 0.f;
            vv[5]  = oks ? sqf(c7s + M7) : 0.f;
            vv[6]  = okp ? sqf(c7p + M7) : 0.f;
            const float v8s = oks ? sqf(c8s + M8) : 0.f;
            const float v8p = okp ? sqf(c8p + M8) : 0.f;
            vv[7]  = v8s + v8p;
            vv[8]  = xw[4]; vv[9] = xw[5]; vv[10] = xw[6]; vv[11] = xw[7];
            xsum   = (xw[4] + xw[5]) + (xw[6] + xw[7]);
        }
        // ---- producer: 40-row input matvec, SGPR weight operands ----
        {
            float a[40];
#pragma unroll
            for (int g = 0; g < 4; ++g)
#pragma unroll
                for (int u = 0; u < 10; ++u) {
                    const float* __restrict__ R = Wd + (g * 10 + u) * 16;
                    float a0 = R[12], a1 = 0.f;
#pragma unroll
                    for (int k = 0; k < 12; k += 2) {
                        a0 = fmaf(vv[k],     R[k],     a0);
                        a1 = fmaf(vv[k + 1], R[k + 1], a1);
                    }
                    a[g * 10 + u] = a0 + a1;
                }
#pragma unroll
            for (int u = 0; u < 10; ++u)
                *reinterpret_cast<float4*>(&gw[u * 4]) =
                    make_float4(a[u], a[10 + u], a[20 + u], a[30 + u]);
            gw[40] = xsum;
        }
        // ---- same-wave DS ordering (single wave: no barrier) ----
        asm volatile("s_waitcnt lgkmcnt(0)" ::: "memory");
        // ---- issue next chunk's x loads (overlap the 16-step consume) ----
        {
            const int nc = (cn + 1 < nChunks) ? cn + 1 : cn;
            posCur = posof(nc);
            loadx(posCur, xA, xB, xC);
        }
        // ---- consume 16 steps (serial chain; TLP hides latency) ----
#pragma unroll 4
        for (int i = 0; i < 16; ++i) step(i);
        if (cn + 1 == warmChunks) {
            accS = 0.f;                        // drop warmup contributions
            if (q == 0) {                      // seg0: exact zero init at s=0
                cs = 0.f;
                hb[lane] = 0.f;
            }
        }
    }

    // ---- group reduction (within 16-lane group; lane0 tree stays clean) ----
    float vA = (jr < 10) ? accS : 0.f;
#pragma unroll
    for (int off = 1; off <= 8; off <<= 1) vA += __shfl_down(vA, off);
    if (jr == 0) P[q * 512 + d * 256 + b0 + c] = vA;
}

// ---------------------------------------------------------------------------
// Kernel 3: out[b] = sigmoid( sum over 16 segments x 2 directions )
// ---------------------------------------------------------------------------
__global__ __launch_bounds__(256) void final_kernel(const float* __restrict__ P,
                                                    float* __restrict__ out)
{
    const int b = threadIdx.x;
    float v = 0.f;
#pragma unroll
    for (int seg = 0; seg < 16; ++seg)
        v += P[seg * 512 + b] + P[seg * 512 + 256 + b];
    out[b] = frcp(1.f + fexp2(-v * L2E));
}

extern "C" void kernel_launch(void* const* d_in, const int* in_sizes, int n_in,
                              void* d_out, int out_size, void* d_ws, size_t ws_size,
                              hipStream_t stream)
{
    const float* x     = (const float*)d_in[0];
    const float* w4    = (const float*)d_in[1];
    const float* w5    = (const float*)d_in[2];
    const float* w6    = (const float*)d_in[3];
    const float* w7    = (const float*)d_in[4];
    const float* w8    = (const float*)d_in[5];
    const float* Wih_f = (const float*)d_in[6];
    const float* Whh_f = (const float*)d_in[7];
    const float* bih_f = (const float*)d_in[8];
    const float* bhh_f = (const float*)d_in[9];
    const float* Wih_r = (const float*)d_in[10];
    const float* Whh_r = (const float*)d_in[11];
    const float* bih_r = (const float*)d_in[12];
    const float* bhh_r = (const float*)d_in[13];

    // ws layout (fp32): P[8192] | MMu[1280] | Wp[1280]
    float*    P   = (float*)d_ws;
    unsigned* MMu = (unsigned*)(P + 8192);
    float*    Wpp = (float*)(MMu + 1280);

    wprep_kernel<<<1, 256, 0, stream>>>(Wih_f, bih_f, bhh_f,
                                        Wih_r, bih_r, bhh_r, Wpp, MMu);
    max_kernel<<<4 * NBATCH, 256, 0, stream>>>(x, w4, w5, w6, w7, w8, MMu);
    lstm_kernel<<<2048, 64, 0, stream>>>(x, w4, w5, w6, w7, w8, MMu,
                                         Wpp, Whh_f, Whh_r, P);
    final_kernel<<<1, NBATCH, 0, stream>>>(P, (float*)d_out);
}

// Round 7
// 240.760 us; speedup vs baseline: 1.1430x; 1.1430x over previous
//
#include <hip/hip_runtime.h>

#define SEQ 4096
#define NBATCH 256

__device__ __forceinline__ float sqf(float v) { return v * v; }
__device__ __forceinline__ float fexp2(float v) { return __builtin_amdgcn_exp2f(v); }
__device__ __forceinline__ float frcp(float v)  { return __builtin_amdgcn_rcpf(v); }

#define L2E 1.4426950408889634f

// order-preserving float<->uint key for atomicMax on floats
__device__ __forceinline__ unsigned fkey(float f) {
    const int b = __float_as_int(f);
    return (unsigned)(b ^ ((b >> 31) | 0x80000000));
}
__device__ __forceinline__ float fival(unsigned k) {
    const int b = (k & 0x80000000u) ? (int)(k ^ 0x80000000u) : (int)(~k);
    return __int_as_float(b);
}

// ---------------------------------------------------------------------------
// Kernel 1a: per-batch conv max -> atomicMax on uint keys.
// (MMu is zeroed by hipMemsetAsync before this kernel.)
// ---------------------------------------------------------------------------
__global__ __launch_bounds__(256) void max_kernel(
    const float* __restrict__ x,
    const float* __restrict__ w4p, const float* __restrict__ w5p,
    const float* __restrict__ w6p, const float* __restrict__ w7p,
    const float* __restrict__ w8p,
    unsigned* __restrict__ MMu)
{
    const int b    = blockIdx.x >> 2;
    const int quar = blockIdx.x & 3;
    const int tid  = threadIdx.x;
    const float* __restrict__ xr = x + (size_t)b * (4 * SEQ);

    float W4[4], W5[5], W6[6], W7[7], W8[8];
#pragma unroll
    for (int k = 0; k < 4; ++k) W4[k] = w4p[k];
#pragma unroll
    for (int k = 0; k < 5; ++k) W5[k] = w5p[k];
#pragma unroll
    for (int k = 0; k < 6; ++k) W6[k] = w6p[k];
#pragma unroll
    for (int k = 0; k < 7; ++k) W7[k] = w7p[k];
#pragma unroll
    for (int k = 0; k < 8; ++k) W8[k] = w8p[k];

    float m4 = -3.4e38f, m5 = -3.4e38f, m6 = -3.4e38f, m7 = -3.4e38f, m8 = -3.4e38f;
    for (int i = quar * (SEQ / 4) + tid; i < (quar + 1) * (SEQ / 4); i += 256) {
        const float4 t0 = *reinterpret_cast<const float4*>(xr + 4 * i);
        const float xa0 = t0.x, xa1 = t0.y, xa2 = t0.z, xa3 = t0.w;
        const float c4 = xa0 * W4[0] + xa1 * W4[1] + xa2 * W4[2] + xa3 * W4[3];
        m4 = fmaxf(m4, c4);
        if (i < SEQ - 1) {
            const float4 t1 = *reinterpret_cast<const float4*>(xr + 4 * i + 4);
            const float xa4 = t1.x, xa5 = t1.y, xa6 = t1.z, xa7 = t1.w;
            const float c5 = xa0*W5[0]+xa1*W5[1]+xa2*W5[2]+xa3*W5[3]+xa4*W5[4];
            const float c6 = xa0*W6[0]+xa1*W6[1]+xa2*W6[2]+xa3*W6[3]+xa4*W6[4]+xa5*W6[5];
            const float c7 = xa0*W7[0]+xa1*W7[1]+xa2*W7[2]+xa3*W7[3]+xa4*W7[4]+xa5*W7[5]+xa6*W7[6];
            const float c8 = xa0*W8[0]+xa1*W8[1]+xa2*W8[2]+xa3*W8[3]+xa4*W8[4]+xa5*W8[5]+xa6*W8[6]+xa7*W8[7];
            m5 = fmaxf(m5, c5); m6 = fmaxf(m6, c6);
            m7 = fmaxf(m7, c7); m8 = fmaxf(m8, c8);
        }
    }
#pragma unroll
    for (int off = 32; off; off >>= 1) {
        m4 = fmaxf(m4, __shfl_down(m4, off));
        m5 = fmaxf(m5, __shfl_down(m5, off));
        m6 = fmaxf(m6, __shfl_down(m6, off));
        m7 = fmaxf(m7, __shfl_down(m7, off));
        m8 = fmaxf(m8, __shfl_down(m8, off));
    }
    __shared__ float wr[4][5];
    if ((tid & 63) == 0) {
        const int w = tid >> 6;
        wr[w][0] = m4; wr[w][1] = m5; wr[w][2] = m6; wr[w][3] = m7; wr[w][4] = m8;
    }
    __syncthreads();
    if (tid < 5) {
        const float m = fmaxf(fmaxf(wr[0][tid], wr[1][tid]),
                              fmaxf(wr[2][tid], wr[3][tid]));
        atomicMax(&MMu[b * 5 + tid], fkey(m));
    }
}

// ---------------------------------------------------------------------------
// Kernel 2 (r7): r5 structure + IN-LOOP register pins.
// r6 post-mortem: SGPR-operand producer regressed (SMEM shares lgkmcnt with
// DS -> wait serialization; a[40] pressure; stride-44 bank conflicts).
// Reverted to r5 (fused conv producer, consumer-side matvecs, conflict-free
// vbuf). The r4-r6 root cause stands: weight values defined by plain loads
// are rematerialized in the hot loop (r5: VGPR=104 < 92 weights + temps,
// ~204 instr/step vs ~112 floor). Fix: asm "+v" pins INSIDE the chunk loop
// -- the asm redefines the values each iteration, making load-remat illegal;
// allocator must keep them resident (budget 256 at waves_per_eu(2,2)).
// Pins cover: 52 input weights, 40 h-weights, 30 conv weights, 5 maxima.
// Math bit-identical to r5 -> absmax 0.
// ---------------------------------------------------------------------------
__global__ __launch_bounds__(64) __attribute__((amdgpu_waves_per_eu(2, 2)))
void lstm_kernel(
    const float* __restrict__ x,
    const float* __restrict__ w4p, const float* __restrict__ w5p,
    const float* __restrict__ w6p, const float* __restrict__ w7p,
    const float* __restrict__ w8p,
    const unsigned* __restrict__ MMu,
    const float* __restrict__ Wih_f, const float* __restrict__ bih_f,
    const float* __restrict__ bhh_f,
    const float* __restrict__ Wih_r, const float* __restrict__ bih_r,
    const float* __restrict__ bhh_r,
    const float* __restrict__ Whh_f, const float* __restrict__ Whh_r,
    float* __restrict__ P)
{
    const int bg   = blockIdx.x & 63;
    const int d    = (blockIdx.x >> 6) & 1;
    const int q    = blockIdx.x >> 7;          // 0..15 = segment
    const int b0   = bg * 4;
    const int lane = threadIdx.x;

    const int s0 = q * 256 - 128;              // negative for q=0 (clamped)
    const int nChunks = 24, warmChunks = 8;    // 16-step chunks, 384 steps

    __shared__ float vbuf[1024];               // [quad k][row][4]: k*256+row*4
    __shared__ float hb[64];                   // [chain][16] broadcast h

    const int c  = lane >> 4;
    const int jr = lane & 15;
    const int jc = (jr < 10) ? jr : 0;

    hb[lane] = 0.f;

    // ---- fold input weights (old wprep math) for (dir d, unit jc) ----
    const float* __restrict__ Wih = d ? Wih_r : Wih_f;
    const float* __restrict__ bi  = d ? bih_r : bih_f;
    const float* __restrict__ bh  = d ? bhh_r : bhh_f;
    float wI[13], wF[13], wG[13], wO[13];
    auto fold = [&](int g, float sc, float* w) {
        const int r = g * 10 + jc;
        const float* __restrict__ W = Wih + r * 24;
        w[0]  = (W[0] + W[1] + W[2] + W[3]) * sc;                // v4s
        w[1]  = (W[4] + W[5] + W[6] + W[7]) * sc;                // v5s
        w[2]  = W[4] * sc;                                       // v5p
        w[3]  = (W[8] + W[9] + W[10] + W[11]) * sc;              // v6s
        w[4]  = (W[8] + W[9]) * sc;                              // v6p
        w[5]  = (W[12] + W[13] + W[14] + W[15]) * sc;            // v7s
        w[6]  = (W[12] + W[13] + W[14]) * sc;                    // v7p
        w[7]  = (W[16] + W[17] + W[18] + W[19]) * sc;            // v8s+v8p
        w[8]  = W[20] * sc; w[9] = W[21] * sc;
        w[10] = W[22] * sc; w[11] = W[23] * sc;                  // x0..x3
        w[12] = (bi[r] + bh[r]) * sc;                            // bias
    };
    fold(0, -L2E, wI); fold(1, -L2E, wF);
    fold(2, -2.f * L2E, wG); fold(3, -L2E, wO);

    // recurrent weights (pre-scaled)
    const float* __restrict__ Whh = d ? Whh_r : Whh_f;
    float hI[10], hF[10], hG[10], hO[10];
#pragma unroll
    for (int k = 0; k < 10; ++k) {
        hI[k] = Whh[jc * 10 + k]        * (-L2E);
        hF[k] = Whh[(10 + jc) * 10 + k] * (-L2E);
        hG[k] = Whh[(20 + jc) * 10 + k] * (-2.f * L2E);
        hO[k] = Whh[(30 + jc) * 10 + k] * (-L2E);
    }

    // ---- staging role: lane stages row (step lane>>2, chain lane&3) ----
    const int lc = lane & 3;
    const int lr = lane >> 2;                  // 0..15
    const float* __restrict__ xr = x + (size_t)(b0 + lc) * (4 * SEQ);

    float W4[4], W5[5], W6[6], W7[7], W8[8];
#pragma unroll
    for (int k = 0; k < 4; ++k) W4[k] = w4p[k];
#pragma unroll
    for (int k = 0; k < 5; ++k) W5[k] = w5p[k];
#pragma unroll
    for (int k = 0; k < 6; ++k) W6[k] = w6p[k];
#pragma unroll
    for (int k = 0; k < 7; ++k) W7[k] = w7p[k];
#pragma unroll
    for (int k = 0; k < 8; ++k) W8[k] = w8p[k];

    float M4 = fival(MMu[(b0 + lc) * 5 + 0]);
    float M5 = fival(MMu[(b0 + lc) * 5 + 1]);
    float M6 = fival(MMu[(b0 + lc) * 5 + 2]);
    float M7 = fival(MMu[(b0 + lc) * 5 + 3]);
    float M8 = fival(MMu[(b0 + lc) * 5 + 4]);

    auto posof = [&](int cn) {
        int sp = s0 + cn * 16 + lr;
        if (sp < 0) sp = 0;                    // q=0 warm region: clamped garbage,
                                               // discarded by the state reset
        return d ? (SEQ - 1 - sp) : sp;
    };
    auto loadx = [&](int pos, float4& A, float4& B, float4& C) {
        B = *reinterpret_cast<const float4*>(xr + 4 * pos);
        A = (pos > 0) ? *reinterpret_cast<const float4*>(xr + 4 * pos - 4)
                      : make_float4(0.f, 0.f, 0.f, 0.f);
        C = (pos < SEQ - 1) ? *reinterpret_cast<const float4*>(xr + 4 * pos + 4)
                            : make_float4(0.f, 0.f, 0.f, 0.f);
    };

    int posCur = posof(0);
    float4 xA, xB, xC;
    loadx(posCur, xA, xB, xC);

    float cs = 0.f, accS = 0.f;

    // one recurrence step; h round-trips through hb (same-wave DS in-order)
    auto step = [&](int i) {
        const int ro = (i * 4 + c) * 4;
        const float4 q0 = *reinterpret_cast<const float4*>(&vbuf[ro]);
        const float4 q1 = *reinterpret_cast<const float4*>(&vbuf[256 + ro]);
        const float4 q2 = *reinterpret_cast<const float4*>(&vbuf[512 + ro]);
        const float  sx = vbuf[768 + ro];
        const float vv[12] = {q0.x, q0.y, q0.z, q0.w,
                              q1.x, q1.y, q1.z, q1.w,
                              q2.x, q2.y, q2.z, q2.w};
        const float4 h03 = *reinterpret_cast<const float4*>(&hb[c * 16 + 0]);
        const float4 h47 = *reinterpret_cast<const float4*>(&hb[c * 16 + 4]);
        const float2 h89 = *reinterpret_cast<const float2*>(&hb[c * 16 + 8]);
        const float hj[10] = {h03.x, h03.y, h03.z, h03.w,
                              h47.x, h47.y, h47.z, h47.w, h89.x, h89.y};
        // in-matvec (same even/odd accumulation order as r3/r4/r5)
        float ei0 = wI[12], ei1 = 0.f, ef0 = wF[12], ef1 = 0.f;
        float eg0 = wG[12], eg1 = 0.f, eo0 = wO[12], eo1 = 0.f;
#pragma unroll
        for (int k = 0; k < 12; k += 2) {
            ei0 = fmaf(vv[k], wI[k], ei0); ei1 = fmaf(vv[k + 1], wI[k + 1], ei1);
            ef0 = fmaf(vv[k], wF[k], ef0); ef1 = fmaf(vv[k + 1], wF[k + 1], ef1);
            eg0 = fmaf(vv[k], wG[k], eg0); eg1 = fmaf(vv[k + 1], wG[k + 1], eg1);
            eo0 = fmaf(vv[k], wO[k], eo0); eo1 = fmaf(vv[k + 1], wO[k + 1], eo1);
        }
        const float si = ei0 + ei1, sf2 = ef0 + ef1;
        const float sg = eg0 + eg1, so2 = eo0 + eo1;
        // h-matvec (same even/odd order)
        float ai0 = si, ai1 = 0.f, af0 = sf2, af1 = 0.f;
        float ag0 = sg, ag1 = 0.f, ao0 = so2, ao1 = 0.f;
#pragma unroll
        for (int k = 0; k < 10; k += 2) {
            ai0 = fmaf(hj[k], hI[k], ai0); ai1 = fmaf(hj[k + 1], hI[k + 1], ai1);
            af0 = fmaf(hj[k], hF[k], af0); af1 = fmaf(hj[k + 1], hF[k + 1], af1);
            ag0 = fmaf(hj[k], hG[k], ag0); ag1 = fmaf(hj[k + 1], hG[k + 1], ag1);
            ao0 = fmaf(hj[k], hO[k], ao0); ao1 = fmaf(hj[k + 1], hO[k + 1], ao1);
        }
        const float eI = ai0 + ai1, eF = af0 + af1;
        const float eG = ag0 + ag1, eO = ao0 + ao1;
        // eI=-l2e*i  eF=-l2e*f  eG=-2l2e*g  eO=-l2e*o
        const float Ai = fexp2(eI);                    // e^-i
        const float Fv = fexp2(eF);                    // e^-f
        const float Bg = fexp2(fminf(eG, 80.f));       // e^-2g (clamped: no inf*0)
        const float Ov = fexp2(eO);                    // e^-o
        const float sf = frcp(1.f + Fv);
        // -2l2e * sigmoid(i)*tanh(g) = (2l2e*Bg - 2l2e) / ((1+Ai)(1+Bg))
        const float it = fmaf(Bg, 2.f * L2E, -2.f * L2E) *
                         frcp((1.f + Ai) * (1.f + Bg));
        cs = fmaf(sf, cs, it);                         // cs = -2l2e * c
        const float Dv = fexp2(fminf(cs, 80.f));       // e^-2c (clamped)
        // sigmoid(o)*tanh(c) = (1-Dv) / ((1+Ov)(1+Dv))
        const float hv = (1.f - Dv) * frcp((1.f + Ov) * (1.f + Dv));
        hb[c * 16 + jr] = hv;                          // jr>=10 -> harmless pad
        accS = fmaf(sx, hv, accS);
    };

    for (int cn = 0; cn < nChunks; ++cn) {
        // ---- IN-LOOP pins: opaque redefinition of all loop-resident weight
        // values. Load-remat becomes illegal; allocator must keep them in
        // VGPRs (or scratch-spill, which it avoids under the 256 budget). ----
        asm volatile("" :
            "+v"(wI[0]), "+v"(wI[1]), "+v"(wI[2]), "+v"(wI[3]), "+v"(wI[4]),
            "+v"(wI[5]), "+v"(wI[6]), "+v"(wI[7]), "+v"(wI[8]), "+v"(wI[9]),
            "+v"(wI[10]), "+v"(wI[11]), "+v"(wI[12]),
            "+v"(wF[0]), "+v"(wF[1]), "+v"(wF[2]), "+v"(wF[3]), "+v"(wF[4]),
            "+v"(wF[5]), "+v"(wF[6]), "+v"(wF[7]), "+v"(wF[8]), "+v"(wF[9]),
            "+v"(wF[10]), "+v"(wF[11]), "+v"(wF[12]));
        asm volatile("" :
            "+v"(wG[0]), "+v"(wG[1]), "+v"(wG[2]), "+v"(wG[3]), "+v"(wG[4]),
            "+v"(wG[5]), "+v"(wG[6]), "+v"(wG[7]), "+v"(wG[8]), "+v"(wG[9]),
            "+v"(wG[10]), "+v"(wG[11]), "+v"(wG[12]),
            "+v"(wO[0]), "+v"(wO[1]), "+v"(wO[2]), "+v"(wO[3]), "+v"(wO[4]),
            "+v"(wO[5]), "+v"(wO[6]), "+v"(wO[7]), "+v"(wO[8]), "+v"(wO[9]),
            "+v"(wO[10]), "+v"(wO[11]), "+v"(wO[12]));
        asm volatile("" :
            "+v"(hI[0]), "+v"(hI[1]), "+v"(hI[2]), "+v"(hI[3]), "+v"(hI[4]),
            "+v"(hI[5]), "+v"(hI[6]), "+v"(hI[7]), "+v"(hI[8]), "+v"(hI[9]),
            "+v"(hF[0]), "+v"(hF[1]), "+v"(hF[2]), "+v"(hF[3]), "+v"(hF[4]),
            "+v"(hF[5]), "+v"(hF[6]), "+v"(hF[7]), "+v"(hF[8]), "+v"(hF[9]));
        asm volatile("" :
            "+v"(hG[0]), "+v"(hG[1]), "+v"(hG[2]), "+v"(hG[3]), "+v"(hG[4]),
            "+v"(hG[5]), "+v"(hG[6]), "+v"(hG[7]), "+v"(hG[8]), "+v"(hG[9]),
            "+v"(hO[0]), "+v"(hO[1]), "+v"(hO[2]), "+v"(hO[3]), "+v"(hO[4]),
            "+v"(hO[5]), "+v"(hO[6]), "+v"(hO[7]), "+v"(hO[8]), "+v"(hO[9]));
        asm volatile("" :
            "+v"(W4[0]), "+v"(W4[1]), "+v"(W4[2]), "+v"(W4[3]),
            "+v"(W5[0]), "+v"(W5[1]), "+v"(W5[2]), "+v"(W5[3]), "+v"(W5[4]),
            "+v"(W6[0]), "+v"(W6[1]), "+v"(W6[2]), "+v"(W6[3]), "+v"(W6[4]),
            "+v"(W6[5]),
            "+v"(W7[0]), "+v"(W7[1]), "+v"(W7[2]), "+v"(W7[3]), "+v"(W7[4]),
            "+v"(W7[5]), "+v"(W7[6]),
            "+v"(W8[0]), "+v"(W8[1]), "+v"(W8[2]), "+v"(W8[3]), "+v"(W8[4]),
            "+v"(W8[5]), "+v"(W8[6]), "+v"(W8[7]));
        asm volatile("" :
            "+v"(M4), "+v"(M5), "+v"(M6), "+v"(M7), "+v"(M8));

        // ---- conv for this chunk's row (old scatter math, exact order) ----
        {
            const bool okp = posCur > 0, oks = posCur < SEQ - 1;
            float xw[12];
            xw[0] = xA.x; xw[1] = xA.y; xw[2]  = xA.z; xw[3]  = xA.w;
            xw[4] = xB.x; xw[5] = xB.y; xw[6]  = xB.z; xw[7]  = xB.w;
            xw[8] = xC.x; xw[9] = xC.y; xw[10] = xC.z; xw[11] = xC.w;

            float c4s = 0.f, c5s = 0.f, c6s = 0.f, c7s = 0.f, c8s = 0.f;
            float c5p = 0.f, c6p = 0.f, c7p = 0.f, c8p = 0.f;
#pragma unroll
            for (int t = 0; t < 4; ++t) c4s += xw[4 + t] * W4[t];
#pragma unroll
            for (int t = 0; t < 5; ++t) { c5s += xw[4 + t] * W5[t]; c5p += xw[t] * W5[t]; }
#pragma unroll
            for (int t = 0; t < 6; ++t) { c6s += xw[4 + t] * W6[t]; c6p += xw[t] * W6[t]; }
#pragma unroll
            for (int t = 0; t < 7; ++t) { c7s += xw[4 + t] * W7[t]; c7p += xw[t] * W7[t]; }
#pragma unroll
            for (int t = 0; t < 8; ++t) { c8s += xw[4 + t] * W8[t]; c8p += xw[t] * W8[t]; }

            const float v4s = sqf(c4s + M4);
            const float v5s = oks ? sqf(c5s + M5) : 0.f;
            const float v6s = oks ? sqf(c6s + M6) : 0.f;
            const float v7s = oks ? sqf(c7s + M7) : 0.f;
            const float v8s = oks ? sqf(c8s + M8) : 0.f;
            const float v5p = okp ? sqf(c5p + M5) : 0.f;
            const float v6p = okp ? sqf(c6p + M6) : 0.f;
            const float v7p = okp ? sqf(c7p + M7) : 0.f;
            const float v8p = okp ? sqf(c8p + M8) : 0.f;
            const float xsum = (xw[4] + xw[5]) + (xw[6] + xw[7]);

            *reinterpret_cast<float4*>(&vbuf[lane * 4]) =
                make_float4(v4s, v5s, v5p, v6s);
            *reinterpret_cast<float4*>(&vbuf[256 + lane * 4]) =
                make_float4(v6p, v7s, v7p, v8s + v8p);
            *reinterpret_cast<float4*>(&vbuf[512 + lane * 4]) =
                make_float4(xw[4], xw[5], xw[6], xw[7]);
            vbuf[768 + lane * 4] = xsum;
        }
        // ---- same-wave DS ordering (single wave: no barrier) ----
        asm volatile("s_waitcnt lgkmcnt(0)" ::: "memory");
        // ---- issue next chunk's x loads (overlap the 16-step consume) ----
        {
            const int nc = (cn + 1 < nChunks) ? cn + 1 : cn;
            posCur = posof(nc);
            loadx(posCur, xA, xB, xC);
        }
        // ---- consume 16 steps (serial chain; TLP + in-matvec hide latency) ----
#pragma unroll 4
        for (int i = 0; i < 16; ++i) step(i);
        if (cn + 1 == warmChunks) {
            accS = 0.f;                        // drop warmup contributions
            if (q == 0) {                      // seg0: exact zero init at s=0
                cs = 0.f;
                hb[lane] = 0.f;
            }
        }
    }

    // ---- group reduction (within 16-lane group; lane0 tree stays clean) ----
    float vA = (jr < 10) ? accS : 0.f;
#pragma unroll
    for (int off = 1; off <= 8; off <<= 1) vA += __shfl_down(vA, off);
    if (jr == 0) P[q * 512 + d * 256 + b0 + c] = vA;
}

// ---------------------------------------------------------------------------
// Kernel 3: out[b] = sigmoid( sum over 16 segments x 2 directions )
// ---------------------------------------------------------------------------
__global__ __launch_bounds__(256) void final_kernel(const float* __restrict__ P,
                                                    float* __restrict__ out)
{
    const int b = threadIdx.x;
    float v = 0.f;
#pragma unroll
    for (int seg = 0; seg < 16; ++seg)
        v += P[seg * 512 + b] + P[seg * 512 + 256 + b];
    out[b] = frcp(1.f + fexp2(-v * L2E));
}

extern "C" void kernel_launch(void* const* d_in, const int* in_sizes, int n_in,
                              void* d_out, int out_size, void* d_ws, size_t ws_size,
                              hipStream_t stream)
{
    const float* x     = (const float*)d_in[0];
    const float* w4    = (const float*)d_in[1];
    const float* w5    = (const float*)d_in[2];
    const float* w6    = (const float*)d_in[3];
    const float* w7    = (const float*)d_in[4];
    const float* w8    = (const float*)d_in[5];
    const float* Wih_f = (const float*)d_in[6];
    const float* Whh_f = (const float*)d_in[7];
    const float* bih_f = (const float*)d_in[8];
    const float* bhh_f = (const float*)d_in[9];
    const float* Wih_r = (const float*)d_in[10];
    const float* Whh_r = (const float*)d_in[11];
    const float* bih_r = (const float*)d_in[12];
    const float* bhh_r = (const float*)d_in[13];

    // ws layout (fp32): P[8192] | MMu[1280]
    float*    P   = (float*)d_ws;
    unsigned* MMu = (unsigned*)(P + 8192);

    hipMemsetAsync(MMu, 0, 1280 * sizeof(unsigned), stream);
    max_kernel<<<4 * NBATCH, 256, 0, stream>>>(x, w4, w5, w6, w7, w8, MMu);
    lstm_kernel<<<2048, 64, 0, stream>>>(x, w4, w5, w6, w7, w8, MMu,
                                         Wih_f, bih_f, bhh_f,
                                         Wih_r, bih_r, bhh_r,
                                         Whh_f, Whh_r, P);
    final_kernel<<<1, NBATCH, 0, stream>>>(P, (float*)d_out);
}

// Round 8
// 237.573 us; speedup vs baseline: 1.1583x; 1.0134x over previous
//
#include <hip/hip_runtime.h>

#define SEQ 4096
#define NBATCH 256

typedef float v2f __attribute__((ext_vector_type(2)));

__device__ __forceinline__ float sqf(float v) { return v * v; }
__device__ __forceinline__ float fexp2(float v) { return __builtin_amdgcn_exp2f(v); }
__device__ __forceinline__ float frcp(float v)  { return __builtin_amdgcn_rcpf(v); }

#define L2E 1.4426950408889634f

// ---------------------------------------------------------------------------
// Kernel 1a: per-batch conv max. Each (batch, quarter) block writes its 5
// maxima to its own slot Mq[(b*4+quar)*5 + j] -- no atomics, no memset, no
// key encoding. The lstm kernel reduces the 4 quarter slots (max is
// order-independent -> bit-identical to the old atomic reduction).
// ---------------------------------------------------------------------------
__global__ __launch_bounds__(256) void max_kernel(
    const float* __restrict__ x,
    const float* __restrict__ w4p, const float* __restrict__ w5p,
    const float* __restrict__ w6p, const float* __restrict__ w7p,
    const float* __restrict__ w8p,
    float* __restrict__ Mq)
{
    const int b    = blockIdx.x >> 2;
    const int quar = blockIdx.x & 3;
    const int tid  = threadIdx.x;
    const float* __restrict__ xr = x + (size_t)b * (4 * SEQ);

    float W4[4], W5[5], W6[6], W7[7], W8[8];
#pragma unroll
    for (int k = 0; k < 4; ++k) W4[k] = w4p[k];
#pragma unroll
    for (int k = 0; k < 5; ++k) W5[k] = w5p[k];
#pragma unroll
    for (int k = 0; k < 6; ++k) W6[k] = w6p[k];
#pragma unroll
    for (int k = 0; k < 7; ++k) W7[k] = w7p[k];
#pragma unroll
    for (int k = 0; k < 8; ++k) W8[k] = w8p[k];

    float m4 = -3.4e38f, m5 = -3.4e38f, m6 = -3.4e38f, m7 = -3.4e38f, m8 = -3.4e38f;
    for (int i = quar * (SEQ / 4) + tid; i < (quar + 1) * (SEQ / 4); i += 256) {
        const float4 t0 = *reinterpret_cast<const float4*>(xr + 4 * i);
        const float xa0 = t0.x, xa1 = t0.y, xa2 = t0.z, xa3 = t0.w;
        const float c4 = xa0 * W4[0] + xa1 * W4[1] + xa2 * W4[2] + xa3 * W4[3];
        m4 = fmaxf(m4, c4);
        if (i < SEQ - 1) {
            const float4 t1 = *reinterpret_cast<const float4*>(xr + 4 * i + 4);
            const float xa4 = t1.x, xa5 = t1.y, xa6 = t1.z, xa7 = t1.w;
            const float c5 = xa0*W5[0]+xa1*W5[1]+xa2*W5[2]+xa3*W5[3]+xa4*W5[4];
            const float c6 = xa0*W6[0]+xa1*W6[1]+xa2*W6[2]+xa3*W6[3]+xa4*W6[4]+xa5*W6[5];
            const float c7 = xa0*W7[0]+xa1*W7[1]+xa2*W7[2]+xa3*W7[3]+xa4*W7[4]+xa5*W7[5]+xa6*W7[6];
            const float c8 = xa0*W8[0]+xa1*W8[1]+xa2*W8[2]+xa3*W8[3]+xa4*W8[4]+xa5*W8[5]+xa6*W8[6]+xa7*W8[7];
            m5 = fmaxf(m5, c5); m6 = fmaxf(m6, c6);
            m7 = fmaxf(m7, c7); m8 = fmaxf(m8, c8);
        }
    }
#pragma unroll
    for (int off = 32; off; off >>= 1) {
        m4 = fmaxf(m4, __shfl_down(m4, off));
        m5 = fmaxf(m5, __shfl_down(m5, off));
        m6 = fmaxf(m6, __shfl_down(m6, off));
        m7 = fmaxf(m7, __shfl_down(m7, off));
        m8 = fmaxf(m8, __shfl_down(m8, off));
    }
    __shared__ float wr[4][5];
    if ((tid & 63) == 0) {
        const int w = tid >> 6;
        wr[w][0] = m4; wr[w][1] = m5; wr[w][2] = m6; wr[w][3] = m7; wr[w][4] = m8;
    }
    __syncthreads();
    if (tid < 5) {
        const float m = fmaxf(fmaxf(wr[0][tid], wr[1][tid]),
                              fmaxf(wr[2][tid], wr[3][tid]));
        Mq[blockIdx.x * 5 + tid] = m;
    }
}

// ---------------------------------------------------------------------------
// Kernel 2 (r8): r7 structure with the step matvecs re-packed as v2f
// (v_pk_fma_f32). r7 post-mortem: scalar step issues ~420 busy-cyc/step vs
// ~280-330 floor; r2's v2f consumer measured ~326 busy-cyc/step INCLUDING
// a heavy producer -> packed fp32 halves FMA issue slots (88 -> 44) and we
// are issue-slot-bound (r1/r3 invariant). Gate pairs {i,f} and {g,o};
// component-wise order bit-identical to r7 (even/odd split, in-sum
// completed before h-matvec seed -- r2's verified pattern, absmax 0.0).
// In-loop asm pins (r7) kept, now on the v2f weight values.
// Also: per-quarter maxima (no atomics / memset); fused conv producer,
// conflict-free vbuf, hb broadcast h state; nseg=16, own=256, warm=128;
// seg0 exact reset; 2048 x 64, 2 waves/SIMD.
// ---------------------------------------------------------------------------
__global__ __launch_bounds__(64) __attribute__((amdgpu_waves_per_eu(2, 2)))
void lstm_kernel(
    const float* __restrict__ x,
    const float* __restrict__ w4p, const float* __restrict__ w5p,
    const float* __restrict__ w6p, const float* __restrict__ w7p,
    const float* __restrict__ w8p,
    const float* __restrict__ Mq,
    const float* __restrict__ Wih_f, const float* __restrict__ bih_f,
    const float* __restrict__ bhh_f,
    const float* __restrict__ Wih_r, const float* __restrict__ bih_r,
    const float* __restrict__ bhh_r,
    const float* __restrict__ Whh_f, const float* __restrict__ Whh_r,
    float* __restrict__ P)
{
    const int bg   = blockIdx.x & 63;
    const int d    = (blockIdx.x >> 6) & 1;
    const int q    = blockIdx.x >> 7;          // 0..15 = segment
    const int b0   = bg * 4;
    const int lane = threadIdx.x;

    const int s0 = q * 256 - 128;              // negative for q=0 (clamped)
    const int nChunks = 24, warmChunks = 8;    // 16-step chunks, 384 steps

    __shared__ float vbuf[1024];               // [quad k][row][4]: k*256+row*4
    __shared__ float hb[64];                   // [chain][16] broadcast h

    const int c  = lane >> 4;
    const int jr = lane & 15;
    const int jc = (jr < 10) ? jr : 0;

    hb[lane] = 0.f;

    // ---- fold input weights (r7 math) for (dir d, unit jc), pack v2f ----
    const float* __restrict__ Wih = d ? Wih_r : Wih_f;
    const float* __restrict__ bi  = d ? bih_r : bih_f;
    const float* __restrict__ bh  = d ? bhh_r : bhh_f;
    float wI[13], wF[13], wG[13], wO[13];
    auto fold = [&](int g, float sc, float* w) {
        const int r = g * 10 + jc;
        const float* __restrict__ W = Wih + r * 24;
        w[0]  = (W[0] + W[1] + W[2] + W[3]) * sc;                // v4s
        w[1]  = (W[4] + W[5] + W[6] + W[7]) * sc;                // v5s
        w[2]  = W[4] * sc;                                       // v5p
        w[3]  = (W[8] + W[9] + W[10] + W[11]) * sc;              // v6s
        w[4]  = (W[8] + W[9]) * sc;                              // v6p
        w[5]  = (W[12] + W[13] + W[14] + W[15]) * sc;            // v7s
        w[6]  = (W[12] + W[13] + W[14]) * sc;                    // v7p
        w[7]  = (W[16] + W[17] + W[18] + W[19]) * sc;            // v8s+v8p
        w[8]  = W[20] * sc; w[9] = W[21] * sc;
        w[10] = W[22] * sc; w[11] = W[23] * sc;                  // x0..x3
        w[12] = (bi[r] + bh[r]) * sc;                            // bias
    };
    fold(0, -L2E, wI); fold(1, -L2E, wF);
    fold(2, -2.f * L2E, wG); fold(3, -L2E, wO);

    v2f wIF[13], wGO[13];
#pragma unroll
    for (int k = 0; k < 13; ++k) {
        wIF[k] = (v2f){wI[k], wF[k]};
        wGO[k] = (v2f){wG[k], wO[k]};
    }

    // recurrent weights (pre-scaled), packed
    const float* __restrict__ Whh = d ? Whh_r : Whh_f;
    v2f hIF[10], hGO[10];
#pragma unroll
    for (int k = 0; k < 10; ++k) {
        hIF[k] = (v2f){Whh[jc * 10 + k]        * (-L2E),
                       Whh[(10 + jc) * 10 + k] * (-L2E)};
        hGO[k] = (v2f){Whh[(20 + jc) * 10 + k] * (-2.f * L2E),
                       Whh[(30 + jc) * 10 + k] * (-L2E)};
    }

    // ---- staging role: lane stages row (step lane>>2, chain lane&3) ----
    const int lc = lane & 3;
    const int lr = lane >> 2;                  // 0..15
    const float* __restrict__ xr = x + (size_t)(b0 + lc) * (4 * SEQ);

    float W4[4], W5[5], W6[6], W7[7], W8[8];
#pragma unroll
    for (int k = 0; k < 4; ++k) W4[k] = w4p[k];
#pragma unroll
    for (int k = 0; k < 5; ++k) W5[k] = w5p[k];
#pragma unroll
    for (int k = 0; k < 6; ++k) W6[k] = w6p[k];
#pragma unroll
    for (int k = 0; k < 7; ++k) W7[k] = w7p[k];
#pragma unroll
    for (int k = 0; k < 8; ++k) W8[k] = w8p[k];

    // per-quarter maxima -> max of 4 (order-independent == old atomic)
    const float* __restrict__ Mb = Mq + (size_t)(b0 + lc) * 20;
    float M4 = fmaxf(fmaxf(Mb[0],  Mb[5]),  fmaxf(Mb[10], Mb[15]));
    float M5 = fmaxf(fmaxf(Mb[1],  Mb[6]),  fmaxf(Mb[11], Mb[16]));
    float M6 = fmaxf(fmaxf(Mb[2],  Mb[7]),  fmaxf(Mb[12], Mb[17]));
    float M7 = fmaxf(fmaxf(Mb[3],  Mb[8]),  fmaxf(Mb[13], Mb[18]));
    float M8 = fmaxf(fmaxf(Mb[4],  Mb[9]),  fmaxf(Mb[14], Mb[19]));

    auto posof = [&](int cn) {
        int sp = s0 + cn * 16 + lr;
        if (sp < 0) sp = 0;                    // q=0 warm region: clamped garbage,
                                               // discarded by the state reset
        return d ? (SEQ - 1 - sp) : sp;
    };
    auto loadx = [&](int pos, float4& A, float4& B, float4& C) {
        B = *reinterpret_cast<const float4*>(xr + 4 * pos);
        A = (pos > 0) ? *reinterpret_cast<const float4*>(xr + 4 * pos - 4)
                      : make_float4(0.f, 0.f, 0.f, 0.f);
        C = (pos < SEQ - 1) ? *reinterpret_cast<const float4*>(xr + 4 * pos + 4)
                            : make_float4(0.f, 0.f, 0.f, 0.f);
    };

    int posCur = posof(0);
    float4 xA, xB, xC;
    loadx(posCur, xA, xB, xC);

    float cs = 0.f, accS = 0.f;

    // one recurrence step; h round-trips through hb (same-wave DS in-order)
    auto step = [&](int i) {
        const int ro = (i * 4 + c) * 4;
        const float4 q0 = *reinterpret_cast<const float4*>(&vbuf[ro]);
        const float4 q1 = *reinterpret_cast<const float4*>(&vbuf[256 + ro]);
        const float4 q2 = *reinterpret_cast<const float4*>(&vbuf[512 + ro]);
        const float  sx = vbuf[768 + ro];
        const float vv[12] = {q0.x, q0.y, q0.z, q0.w,
                              q1.x, q1.y, q1.z, q1.w,
                              q2.x, q2.y, q2.z, q2.w};
        const float4 h03 = *reinterpret_cast<const float4*>(&hb[c * 16 + 0]);
        const float4 h47 = *reinterpret_cast<const float4*>(&hb[c * 16 + 4]);
        const float2 h89 = *reinterpret_cast<const float2*>(&hb[c * 16 + 8]);
        const float hj[10] = {h03.x, h03.y, h03.z, h03.w,
                              h47.x, h47.y, h47.z, h47.w, h89.x, h89.y};
        // in-matvec, packed {i,f}/{g,o} (components == r7 scalar order)
        v2f eIF0 = wIF[12], eIF1 = (v2f){0.f, 0.f};
        v2f eGO0 = wGO[12], eGO1 = (v2f){0.f, 0.f};
#pragma unroll
        for (int k = 0; k < 12; k += 2) {
            const v2f v0 = (v2f){vv[k], vv[k]};
            const v2f v1 = (v2f){vv[k + 1], vv[k + 1]};
            eIF0 += v0 * wIF[k]; eIF1 += v1 * wIF[k + 1];
            eGO0 += v0 * wGO[k]; eGO1 += v1 * wGO[k + 1];
        }
        // complete in-sum BEFORE h seed (r7/r2 order)
        v2f aIF0 = eIF0 + eIF1, aIF1 = (v2f){0.f, 0.f};
        v2f aGO0 = eGO0 + eGO1, aGO1 = (v2f){0.f, 0.f};
#pragma unroll
        for (int k = 0; k < 10; k += 2) {
            const v2f h0 = (v2f){hj[k], hj[k]};
            const v2f h1 = (v2f){hj[k + 1], hj[k + 1]};
            aIF0 += h0 * hIF[k]; aIF1 += h1 * hIF[k + 1];
            aGO0 += h0 * hGO[k]; aGO1 += h1 * hGO[k + 1];
        }
        const v2f eIF = aIF0 + aIF1, eGO = aGO0 + aGO1;
        // eIF.x=-l2e*i  eIF.y=-l2e*f  eGO.x=-2l2e*g  eGO.y=-l2e*o
        const float Ai = fexp2(eIF.x);                 // e^-i
        const float Fv = fexp2(eIF.y);                 // e^-f
        const float Bg = fexp2(fminf(eGO.x, 80.f));    // e^-2g (clamped: no inf*0)
        const float Ov = fexp2(eGO.y);                 // e^-o
        const float sf = frcp(1.f + Fv);
        // -2l2e * sigmoid(i)*tanh(g) = (2l2e*Bg - 2l2e) / ((1+Ai)(1+Bg))
        const float it = fmaf(Bg, 2.f * L2E, -2.f * L2E) *
                         frcp((1.f + Ai) * (1.f + Bg));
        cs = fmaf(sf, cs, it);                         // cs = -2l2e * c
        const float Dv = fexp2(fminf(cs, 80.f));       // e^-2c (clamped)
        // sigmoid(o)*tanh(c) = (1-Dv) / ((1+Ov)(1+Dv))
        const float hv = (1.f - Dv) * frcp((1.f + Ov) * (1.f + Dv));
        hb[c * 16 + jr] = hv;                          // jr>=10 -> harmless pad
        accS = fmaf(sx, hv, accS);
    };

    for (int cn = 0; cn < nChunks; ++cn) {
        // ---- IN-LOOP pins: opaque redefinition -> load-remat illegal ----
        asm volatile("" :
            "+v"(wIF[0]), "+v"(wIF[1]), "+v"(wIF[2]), "+v"(wIF[3]),
            "+v"(wIF[4]), "+v"(wIF[5]), "+v"(wIF[6]), "+v"(wIF[7]),
            "+v"(wIF[8]), "+v"(wIF[9]), "+v"(wIF[10]), "+v"(wIF[11]),
            "+v"(wIF[12]),
            "+v"(wGO[0]), "+v"(wGO[1]), "+v"(wGO[2]), "+v"(wGO[3]),
            "+v"(wGO[4]), "+v"(wGO[5]), "+v"(wGO[6]), "+v"(wGO[7]),
            "+v"(wGO[8]), "+v"(wGO[9]), "+v"(wGO[10]), "+v"(wGO[11]),
            "+v"(wGO[12]));
        asm volatile("" :
            "+v"(hIF[0]), "+v"(hIF[1]), "+v"(hIF[2]), "+v"(hIF[3]),
            "+v"(hIF[4]), "+v"(hIF[5]), "+v"(hIF[6]), "+v"(hIF[7]),
            "+v"(hIF[8]), "+v"(hIF[9]),
            "+v"(hGO[0]), "+v"(hGO[1]), "+v"(hGO[2]), "+v"(hGO[3]),
            "+v"(hGO[4]), "+v"(hGO[5]), "+v"(hGO[6]), "+v"(hGO[7]),
            "+v"(hGO[8]), "+v"(hGO[9]));
        asm volatile("" :
            "+v"(W4[0]), "+v"(W4[1]), "+v"(W4[2]), "+v"(W4[3]),
            "+v"(W5[0]), "+v"(W5[1]), "+v"(W5[2]), "+v"(W5[3]), "+v"(W5[4]),
            "+v"(W6[0]), "+v"(W6[1]), "+v"(W6[2]), "+v"(W6[3]), "+v"(W6[4]),
            "+v"(W6[5]),
            "+v"(W7[0]), "+v"(W7[1]), "+v"(W7[2]), "+v"(W7[3]), "+v"(W7[4]),
            "+v"(W7[5]), "+v"(W7[6]),
            "+v"(W8[0]), "+v"(W8[1]), "+v"(W8[2]), "+v"(W8[3]), "+v"(W8[4]),
            "+v"(W8[5]), "+v"(W8[6]), "+v"(W8[7]));
        asm volatile("" :
            "+v"(M4), "+v"(M5), "+v"(M6), "+v"(M7), "+v"(M8));

        // ---- conv for this chunk's row (old scatter math, exact order) ----
        {
            const bool okp = posCur > 0, oks = posCur < SEQ - 1;
            float xw[12];
            xw[0] = xA.x; xw[1] = xA.y; xw[2]  = xA.z; xw[3]  = xA.w;
            xw[4] = xB.x; xw[5] = xB.y; xw[6]  = xB.z; xw[7]  = xB.w;
            xw[8] = xC.x; xw[9] = xC.y; xw[10] = xC.z; xw[11] = xC.w;

            float c4s = 0.f, c5s = 0.f, c6s = 0.f, c7s = 0.f, c8s = 0.f;
            float c5p = 0.f, c6p = 0.f, c7p = 0.f, c8p = 0.f;
#pragma unroll
            for (int t = 0; t < 4; ++t) c4s += xw[4 + t] * W4[t];
#pragma unroll
            for (int t = 0; t < 5; ++t) { c5s += xw[4 + t] * W5[t]; c5p += xw[t] * W5[t]; }
#pragma unroll
            for (int t = 0; t < 6; ++t) { c6s += xw[4 + t] * W6[t]; c6p += xw[t] * W6[t]; }
#pragma unroll
            for (int t = 0; t < 7; ++t) { c7s += xw[4 + t] * W7[t]; c7p += xw[t] * W7[t]; }
#pragma unroll
            for (int t = 0; t < 8; ++t) { c8s += xw[4 + t] * W8[t]; c8p += xw[t] * W8[t]; }

            const float v4s = sqf(c4s + M4);
            const float v5s = oks ? sqf(c5s + M5) : 0.f;
            const float v6s = oks ? sqf(c6s + M6) : 0.f;
            const float v7s = oks ? sqf(c7s + M7) : 0.f;
            const float v8s = oks ? sqf(c8s + M8) : 0.f;
            const float v5p = okp ? sqf(c5p + M5) : 0.f;
            const float v6p = okp ? sqf(c6p + M6) : 0.f;
            const float v7p = okp ? sqf(c7p + M7) : 0.f;
            const float v8p = okp ? sqf(c8p + M8) : 0.f;
            const float xsum = (xw[4] + xw[5]) + (xw[6] + xw[7]);

            *reinterpret_cast<float4*>(&vbuf[lane * 4]) =
                make_float4(v4s, v5s, v5p, v6s);
            *reinterpret_cast<float4*>(&vbuf[256 + lane * 4]) =
                make_float4(v6p, v7s, v7p, v8s + v8p);
            *reinterpret_cast<float4*>(&vbuf[512 + lane * 4]) =
                make_float4(xw[4], xw[5], xw[6], xw[7]);
            vbuf[768 + lane * 4] = xsum;
        }
        // ---- same-wave DS ordering (single wave: no barrier) ----
        asm volatile("s_waitcnt lgkmcnt(0)" ::: "memory");
        // ---- issue next chunk's x loads (overlap the 16-step consume) ----
        {
            const int nc = (cn + 1 < nChunks) ? cn + 1 : cn;
            posCur = posof(nc);
            loadx(posCur, xA, xB, xC);
        }
        // ---- consume 16 steps (serial chain; TLP hides latency) ----
#pragma unroll 4
        for (int i = 0; i < 16; ++i) step(i);
        if (cn + 1 == warmChunks) {
            accS = 0.f;                        // drop warmup contributions
            if (q == 0) {                      // seg0: exact zero init at s=0
                cs = 0.f;
                hb[lane] = 0.f;
            }
        }
    }

    // ---- group reduction (within 16-lane group; lane0 tree stays clean) ----
    float vA = (jr < 10) ? accS : 0.f;
#pragma unroll
    for (int off = 1; off <= 8; off <<= 1) vA += __shfl_down(vA, off);
    if (jr == 0) P[q * 512 + d * 256 + b0 + c] = vA;
}

// ---------------------------------------------------------------------------
// Kernel 3: out[b] = sigmoid( sum over 16 segments x 2 directions )
// ---------------------------------------------------------------------------
__global__ __launch_bounds__(256) void final_kernel(const float* __restrict__ P,
                                                    float* __restrict__ out)
{
    const int b = threadIdx.x;
    float v = 0.f;
#pragma unroll
    for (int seg = 0; seg < 16; ++seg)
        v += P[seg * 512 + b] + P[seg * 512 + 256 + b];
    out[b] = frcp(1.f + fexp2(-v * L2E));
}

extern "C" void kernel_launch(void* const* d_in, const int* in_sizes, int n_in,
                              void* d_out, int out_size, void* d_ws, size_t ws_size,
                              hipStream_t stream)
{
    const float* x     = (const float*)d_in[0];
    const float* w4    = (const float*)d_in[1];
    const float* w5    = (const float*)d_in[2];
    const float* w6    = (const float*)d_in[3];
    const float* w7    = (const float*)d_in[4];
    const float* w8    = (const float*)d_in[5];
    const float* Wih_f = (const float*)d_in[6];
    const float* Whh_f = (const float*)d_in[7];
    const float* bih_f = (const float*)d_in[8];
    const float* bhh_f = (const float*)d_in[9];
    const float* Wih_r = (const float*)d_in[10];
    const float* Whh_r = (const float*)d_in[11];
    const float* bih_r = (const float*)d_in[12];
    const float* bhh_r = (const float*)d_in[13];

    // ws layout (fp32): P[8192] | Mq[5120]
    float* P  = (float*)d_ws;
    float* Mq = P + 8192;

    max_kernel<<<4 * NBATCH, 256, 0, stream>>>(x, w4, w5, w6, w7, w8, Mq);
    lstm_kernel<<<2048, 64, 0, stream>>>(x, w4, w5, w6, w7, w8, Mq,
                                         Wih_f, bih_f, bhh_f,
                                         Wih_r, bih_r, bhh_r,
                                         Whh_f, Whh_r, P);
    final_kernel<<<1, NBATCH, 0, stream>>>(P, (float*)d_out);
}